// Round 1
// baseline (179.293 us; speedup 1.0000x reference)
//
#include <hip/hip_runtime.h>
#include <math.h>
#include <string.h>

#define HH 2048
#define WW 2048
#define TROWS 8

struct Wts { float w[17][5]; };

// angle index a: 0 -> -10deg, 1 -> 0deg, 2 -> +10deg
// per-kernel-row first nonzero tap (analytically derived from the rotated-line
// closed form: k[i][j] = max(0, 1-|cos10*(j-2) -/+ sin10*(i-8)|)); validated at
// runtime on host, dense fallback if mismatch.
__host__ __device__ constexpr int js_fn(int a, int i) {
  return (a == 1) ? 2
       : (a == 2) ? ((i < 3) ? 0 : (i < 9) ? 1 : (i < 14) ? 2 : 3)
                  : ((i < 3) ? 3 : (i < 8) ? 2 : (i < 14) ? 1 : 0);
}
__host__ __device__ constexpr int nt_fn(int a, int i) {
  return (a == 1) ? 1 : (i == 8) ? 3 : 2;
}

__device__ __forceinline__ float fastrcp(float x) {
#if __has_builtin(__builtin_amdgcn_rcpf)
  return __builtin_amdgcn_rcpf(x);
#else
  return 1.0f / x;
#endif
}

// One guided-filter iteration: Xout = Xin + conv(Yin - Xin, k)/Nrm
// Thread: 4 consecutive cols x TROWS rows. Block: 256 threads -> 1024 cols x 8 rows.
template <int ANGLE, int DENSE>
__global__ __launch_bounds__(256)
void conv_iter(const float* __restrict__ Xin, const float* __restrict__ Yin,
               const float* __restrict__ Nrm, float* __restrict__ Xout, Wts wts)
{
  const int tid = threadIdx.x;
  const int x0  = blockIdx.x * (256 * 4) + tid * 4;
  const int y0  = blockIdx.y * TROWS;
  const size_t img = (size_t)blockIdx.z * ((size_t)HH * WW);
  const float* Xb = Xin + img;
  const float* Yb = Yin + img;

  float acc[TROWS][4];
#pragma unroll
  for (int t = 0; t < TROWS; ++t)
#pragma unroll
    for (int c = 0; c < 4; ++c) acc[t][c] = 0.0f;

  const bool safe = (x0 >= 4) && (x0 + 8 <= WW);

  // Diagonal accumulation: fully unrolled over input rows so every window and
  // accumulator index is compile-time (no scratch).
#pragma unroll
  for (int rr = 0; rr < TROWS + 16; ++rr) {
    const int r = y0 - 8 + rr;             // uniform per block -> scalar branch
    if (r >= 0 && r < HH) {
      const float* xr = Xb + (size_t)r * WW;
      const float* yr = Yb + (size_t)r * WW;
      float win[8];                         // cols x0-2 .. x0+5 of (y - X)
      if (safe) {
        const float2 xa = *(const float2*)(xr + x0 - 2);
        const float4 xb = *(const float4*)(xr + x0);
        const float2 xc = *(const float2*)(xr + x0 + 4);
        const float2 ya = *(const float2*)(yr + x0 - 2);
        const float4 yb = *(const float4*)(yr + x0);
        const float2 yc = *(const float2*)(yr + x0 + 4);
        win[0] = ya.x - xa.x;  win[1] = ya.y - xa.y;
        win[2] = yb.x - xb.x;  win[3] = yb.y - xb.y;
        win[4] = yb.z - xb.z;  win[5] = yb.w - xb.w;
        win[6] = yc.x - xc.x;  win[7] = yc.y - xc.y;
      } else {
#pragma unroll
        for (int m = 0; m < 8; ++m) {
          const int xcol = x0 - 2 + m;
          win[m] = (xcol >= 0 && xcol < WW) ? (yr[xcol] - xr[xcol]) : 0.0f;
        }
      }
#pragma unroll
      for (int t = 0; t < TROWS; ++t) {
        const int i = rr - t;               // compile-time after unrolling
        if (i >= 0 && i <= 16) {
          const int js = DENSE ? 0 : js_fn(ANGLE, i);
          const int nt = DENSE ? 5 : nt_fn(ANGLE, i);
#pragma unroll
          for (int jj = 0; jj < nt; ++jj) {
            const float wv = wts.w[i][js + jj];   // kernarg -> SGPR
#pragma unroll
            for (int c = 0; c < 4; ++c)
              acc[t][c] = fmaf(wv, win[c + js + jj], acc[t][c]);
          }
        }
      }
    }
  }

  float* Ob = Xout + img;
#pragma unroll
  for (int t = 0; t < TROWS; ++t) {
    const int yo = y0 + t;
    const float4 xv = *(const float4*)(Xb + (size_t)yo * WW + x0);
    const float4 nv = *(const float4*)(Nrm + (size_t)yo * WW + x0);
    float4 o;
    o.x = xv.x + acc[t][0] * fastrcp(nv.x);
    o.y = xv.y + acc[t][1] * fastrcp(nv.y);
    o.z = xv.z + acc[t][2] * fastrcp(nv.z);
    o.w = xv.w + acc[t][3] * fastrcp(nv.w);
    *(float4*)(Ob + (size_t)yo * WW + x0) = o;
  }
}

// ---------------- host-side replication of _build_kernels ----------------

static void rotate33(const double* src, double* dst, double ang_deg) {
  const int n = 33;
  const double t = ang_deg * 3.14159265358979323846 / 180.0;
  const double cs = cos(t), sn = sin(t);
  for (int y = 0; y < n; ++y) {
    for (int x = 0; x < n; ++x) {
      const double y0 = y - 16.0, x0 = x - 16.0;
      const double sy = cs * y0 + sn * x0 + 16.0;
      const double sx = -sn * y0 + cs * x0 + 16.0;
      const double fy = floor(sy), fx = floor(sx);
      const int y0i = (int)fy, x0i = (int)fx;
      const double wy = sy - fy, wx = sx - fx;
      double o = 0.0;
      for (int dy = 0; dy < 2; ++dy)
        for (int dx = 0; dx < 2; ++dx) {
          const int yy = y0i + dy, xx = x0i + dx;
          if (yy < 0 || yy >= n || xx < 0 || xx >= n) continue;
          const double wgt = (dy ? wy : 1.0 - wy) * (dx ? wx : 1.0 - wx);
          o += wgt * src[yy * n + xx];
        }
      dst[y * n + x] = o;
    }
  }
}

static void build_K(float K[3][17][5]) {
  const double angs[3] = {-10.0, 0.0, 10.0};
  double base[33 * 33], rot[33 * 33];
  for (int i = 0; i < 33 * 33; ++i) base[i] = 0.0;
  for (int y = 0; y < 33; ++y) base[y * 33 + 16] = 1.0;  // ry==0 path
  for (int a = 0; a < 3; ++a) {
    if (a == 1) memcpy(rot, base, sizeof(rot));          // angle % 360 == 0
    else        rotate33(base, rot, angs[a]);
    double k17[17][17];
    for (int y = 0; y < 17; ++y)
      for (int x = 0; x < 17; ++x) k17[y][x] = rot[(y + 8) * 33 + (x + 8)];
    int r = 0, c = 0;
    for (int y = 0; y < 17; ++y) { bool nz = false; for (int x = 0; x < 17; ++x) if (k17[y][x] != 0.0) nz = true; r += nz; }
    for (int x = 0; x < 17; ++x) { bool nz = false; for (int y = 0; y < 17; ++y) if (k17[y][x] != 0.0) nz = true; c += nz; }
    r = r / 2 * 2; c = c / 2 * 2;
    const int kh = r + 1, kw = c + 1;
    for (int y = 0; y < 17; ++y)
      for (int x = 0; x < 5; ++x) K[a][y][x] = 0.0f;
    if (kh <= 17 && kw <= 5) {
      const int oh = (17 - kh) / 2, ow = (5 - kw) / 2;
      for (int y = 0; y < kh; ++y)
        for (int x = 0; x < kw; ++x)
          K[a][oh + y][ow + x] = (float)k17[8 - r / 2 + y][8 - c / 2 + x];
    }
  }
}

// 0 = structured (constexpr jstart/ntaps hold), 1 = dense 5-tap fallback
static int pick_mode(int a, const float K[17][5]) {
  for (int i = 0; i < 17; ++i) {
    const int js = js_fn(a, i), nt = nt_fn(a, i);
    for (int j = 0; j < 5; ++j)
      if ((j < js || j >= js + nt) && K[i][j] != 0.0f) return 1;
  }
  return 0;
}

template <int A>
static void launch_iter(int mode, const float* Xin, const float* Y, const float* Nrm,
                        float* Xout, const Wts& w, int B, hipStream_t s) {
  dim3 grid(WW / 1024, HH / TROWS, B), block(256);
  if (mode == 0) conv_iter<A, 0><<<grid, block, 0, s>>>(Xin, Y, Nrm, Xout, w);
  else           conv_iter<A, 1><<<grid, block, 0, s>>>(Xin, Y, Nrm, Xout, w);
}

extern "C" void kernel_launch(void* const* d_in, const int* in_sizes, int n_in,
                              void* d_out, int out_size, void* d_ws, size_t ws_size,
                              hipStream_t stream) {
  const float* X  = (const float*)d_in[0];
  const float* Y  = (const float*)d_in[1];
  const float* Nn = (const float*)d_in[3];
  float* out = (float*)d_out;
  float* tmp = (float*)d_ws;   // needs B*H*W*4 = 33.6 MB of scratch
  const size_t HW = (size_t)HH * WW;
  const int B = in_sizes[0] / (int)HW;   // 2

  float K[3][17][5];
  build_K(K);
  Wts w[3];
  for (int a = 0; a < 3; ++a) memcpy(w[a].w, K[a], sizeof(w[a].w));
  const int m0 = pick_mode(0, K[0]);
  const int m1 = pick_mode(1, K[1]);
  const int m2 = pick_mode(2, K[2]);

  // X0=d_in -> d_out -> d_ws -> d_out ; every buffer fully overwritten before read
  launch_iter<0>(m0, X,   Y, Nn,          out, w[0], B, stream);
  launch_iter<1>(m1, out, Y, Nn + HW,     tmp, w[1], B, stream);
  launch_iter<2>(m2, tmp, Y, Nn + 2 * HW, out, w[2], B, stream);
}

// Round 2
// 148.039 us; speedup vs baseline: 1.2111x; 1.2111x over previous
//
#include <hip/hip_runtime.h>
#include <math.h>
#include <string.h>

#define HH 2048
#define WW 2048
#define TROWS 4

struct Wts { float w[17][5]; };

// angle index a: 0 -> -10deg, 1 -> 0deg, 2 -> +10deg
// per-kernel-row first nonzero tap (validated at runtime, dense fallback).
__host__ __device__ constexpr int js_fn(int a, int i) {
  return (a == 1) ? 2
       : (a == 2) ? ((i < 3) ? 0 : (i < 9) ? 1 : (i < 14) ? 2 : 3)
                  : ((i < 3) ? 3 : (i < 8) ? 2 : (i < 14) ? 1 : 0);
}
__host__ __device__ constexpr int nt_fn(int a, int i) {
  return (a == 1) ? 1 : (i == 8) ? 3 : 2;
}

__device__ __forceinline__ float fastrcp(float x) {
#if __has_builtin(__builtin_amdgcn_rcpf)
  return __builtin_amdgcn_rcpf(x);
#else
  return 1.0f / x;
#endif
}

// Difference-space guided filter pass.
//  MODE 0 (first):  P0=X, P1=Y. win = Y-X = D0.  Out = cen - acc/N   (= D1)
//  MODE 1 (middle): P0=D.       win = D.         Out = cen - acc/N   (= D2)
//  MODE 2 (last):   P0=D, P1=Y. win = D.         Out = Ycen - cen + acc/N (= X3)
// Thread: 4 cols x TROWS rows. Block 256 threads -> 1024 cols x TROWS rows.
template <int ANGLE, int DENSE, int MODE>
__global__ __launch_bounds__(256, 8)
void conv_iter(const float* __restrict__ P0, const float* __restrict__ P1,
               const float* __restrict__ Nrm, float* __restrict__ Out, Wts wts)
{
  constexpr bool WIN8 = (DENSE || ANGLE != 1);  // angle 0 kernel = single column
  constexpr int  NW   = WIN8 ? 8 : 4;
  constexpr int  CO   = WIN8 ? 2 : 0;           // center offset inside win

  const int tid = threadIdx.x;
  const int x0  = blockIdx.x * (256 * 4) + tid * 4;
  const int y0  = blockIdx.y * TROWS;
  const size_t img = (size_t)blockIdx.z * ((size_t)HH * WW);
  const float* A = P0 + img;
  const float* B = (MODE == 1) ? nullptr : P1 + img;

  float acc[TROWS][4];
  float cen[TROWS][4];
#pragma unroll
  for (int t = 0; t < TROWS; ++t)
#pragma unroll
    for (int c = 0; c < 4; ++c) { acc[t][c] = 0.0f; cen[t][c] = 0.0f; }

  const bool safe = !WIN8 || ((x0 >= 4) && (x0 + 8 <= WW));

  // Fully unrolled over input rows: window + accumulator indices compile-time.
#pragma unroll
  for (int rr = 0; rr < TROWS + 16; ++rr) {
    const int r = y0 - 8 + rr;              // uniform per block
    if (r >= 0 && r < HH) {
      const float* ar = A + (size_t)r * WW;
      const float* br = (MODE == 0) ? (B + (size_t)r * WW) : nullptr;
      float win[NW];
      if (WIN8) {
        if (safe) {
          const float2 a0 = *(const float2*)(ar + x0 - 2);
          const float4 a1 = *(const float4*)(ar + x0);
          const float2 a2 = *(const float2*)(ar + x0 + 4);
          if (MODE == 0) {
            const float2 b0 = *(const float2*)(br + x0 - 2);
            const float4 b1 = *(const float4*)(br + x0);
            const float2 b2 = *(const float2*)(br + x0 + 4);
            win[0] = b0.x - a0.x;  win[1] = b0.y - a0.y;
            win[2] = b1.x - a1.x;  win[3] = b1.y - a1.y;
            win[4] = b1.z - a1.z;  win[5] = b1.w - a1.w;
            win[6] = b2.x - a2.x;  win[7] = b2.y - a2.y;
          } else {
            win[0] = a0.x;  win[1] = a0.y;
            win[2] = a1.x;  win[3] = a1.y;
            win[4] = a1.z;  win[5] = a1.w;
            win[6] = a2.x;  win[7] = a2.y;
          }
        } else {
#pragma unroll
          for (int m = 0; m < 8; ++m) {
            const int xc = x0 - 2 + m;
            const bool v = (xc >= 0 && xc < WW);
            if (MODE == 0) win[m] = v ? (br[xc] - ar[xc]) : 0.0f;
            else           win[m] = v ? ar[xc] : 0.0f;
          }
        }
      } else {
        const float4 a1 = *(const float4*)(ar + x0);
        if (MODE == 0) {
          const float4 b1 = *(const float4*)(br + x0);
          win[0] = b1.x - a1.x;  win[1] = b1.y - a1.y;
          win[2] = b1.z - a1.z;  win[3] = b1.w - a1.w;
        } else {
          win[0] = a1.x;  win[1] = a1.y;  win[2] = a1.z;  win[3] = a1.w;
        }
      }
#pragma unroll
      for (int t = 0; t < TROWS; ++t) {
        const int i = rr - t;               // compile-time after unrolling
        if (i >= 0 && i <= 16) {
          if (i == 8) {                     // this input row IS output row y0+t
#pragma unroll
            for (int c = 0; c < 4; ++c) cen[t][c] = win[CO + c];
          }
          const int js = DENSE ? 0 : js_fn(ANGLE, i);
          const int nt = DENSE ? 5 : nt_fn(ANGLE, i);
#pragma unroll
          for (int jj = 0; jj < nt; ++jj) {
            const float wv = wts.w[i][js + jj];   // kernarg -> SGPR
            if (wv != 0.0f || !DENSE) {
#pragma unroll
              for (int c = 0; c < 4; ++c)
                acc[t][c] = fmaf(wv, win[(WIN8 ? 0 : -2) + c + js + jj], acc[t][c]);
            }
          }
        }
      }
    }
  }

  float* Ob = Out + img;
#pragma unroll
  for (int t = 0; t < TROWS; ++t) {
    const int yo = y0 + t;
    const float4 nv = *(const float4*)(Nrm + (size_t)yo * WW + x0);
    float4 o;
    if (MODE == 2) {
      const float4 yv = *(const float4*)(B + (size_t)yo * WW + x0);
      o.x = yv.x - cen[t][0] + acc[t][0] * fastrcp(nv.x);
      o.y = yv.y - cen[t][1] + acc[t][1] * fastrcp(nv.y);
      o.z = yv.z - cen[t][2] + acc[t][2] * fastrcp(nv.z);
      o.w = yv.w - cen[t][3] + acc[t][3] * fastrcp(nv.w);
    } else {
      o.x = cen[t][0] - acc[t][0] * fastrcp(nv.x);
      o.y = cen[t][1] - acc[t][1] * fastrcp(nv.y);
      o.z = cen[t][2] - acc[t][2] * fastrcp(nv.z);
      o.w = cen[t][3] - acc[t][3] * fastrcp(nv.w);
    }
    *(float4*)(Ob + (size_t)yo * WW + x0) = o;
  }
}

// ---------------- host-side replication of _build_kernels ----------------

static void rotate33(const double* src, double* dst, double ang_deg) {
  const int n = 33;
  const double t = ang_deg * 3.14159265358979323846 / 180.0;
  const double cs = cos(t), sn = sin(t);
  for (int y = 0; y < n; ++y) {
    for (int x = 0; x < n; ++x) {
      const double y0 = y - 16.0, x0 = x - 16.0;
      const double sy = cs * y0 + sn * x0 + 16.0;
      const double sx = -sn * y0 + cs * x0 + 16.0;
      const double fy = floor(sy), fx = floor(sx);
      const int y0i = (int)fy, x0i = (int)fx;
      const double wy = sy - fy, wx = sx - fx;
      double o = 0.0;
      for (int dy = 0; dy < 2; ++dy)
        for (int dx = 0; dx < 2; ++dx) {
          const int yy = y0i + dy, xx = x0i + dx;
          if (yy < 0 || yy >= n || xx < 0 || xx >= n) continue;
          const double wgt = (dy ? wy : 1.0 - wy) * (dx ? wx : 1.0 - wx);
          o += wgt * src[yy * n + xx];
        }
      dst[y * n + x] = o;
    }
  }
}

static void build_K(float K[3][17][5]) {
  const double angs[3] = {-10.0, 0.0, 10.0};
  double base[33 * 33], rot[33 * 33];
  for (int i = 0; i < 33 * 33; ++i) base[i] = 0.0;
  for (int y = 0; y < 33; ++y) base[y * 33 + 16] = 1.0;  // ry==0 path
  for (int a = 0; a < 3; ++a) {
    if (a == 1) memcpy(rot, base, sizeof(rot));          // angle % 360 == 0
    else        rotate33(base, rot, angs[a]);
    double k17[17][17];
    for (int y = 0; y < 17; ++y)
      for (int x = 0; x < 17; ++x) k17[y][x] = rot[(y + 8) * 33 + (x + 8)];
    int r = 0, c = 0;
    for (int y = 0; y < 17; ++y) { bool nz = false; for (int x = 0; x < 17; ++x) if (k17[y][x] != 0.0) nz = true; r += nz; }
    for (int x = 0; x < 17; ++x) { bool nz = false; for (int y = 0; y < 17; ++y) if (k17[y][x] != 0.0) nz = true; c += nz; }
    r = r / 2 * 2; c = c / 2 * 2;
    const int kh = r + 1, kw = c + 1;
    for (int y = 0; y < 17; ++y)
      for (int x = 0; x < 5; ++x) K[a][y][x] = 0.0f;
    if (kh <= 17 && kw <= 5) {
      const int oh = (17 - kh) / 2, ow = (5 - kw) / 2;
      for (int y = 0; y < kh; ++y)
        for (int x = 0; x < kw; ++x)
          K[a][oh + y][ow + x] = (float)k17[8 - r / 2 + y][8 - c / 2 + x];
    }
  }
}

// 0 = structured (constexpr jstart/ntaps hold), 1 = dense 5-tap fallback
static int pick_mode(int a, const float K[17][5]) {
  for (int i = 0; i < 17; ++i) {
    const int js = js_fn(a, i), nt = nt_fn(a, i);
    for (int j = 0; j < 5; ++j)
      if ((j < js || j >= js + nt) && K[i][j] != 0.0f) return 1;
  }
  return 0;
}

template <int A, int MODE>
static void launch_iter(int dense, const float* P0, const float* P1, const float* Nrm,
                        float* Out, const Wts& w, int B, hipStream_t s) {
  dim3 grid(WW / 1024, HH / TROWS, B), block(256);
  if (dense == 0) conv_iter<A, 0, MODE><<<grid, block, 0, s>>>(P0, P1, Nrm, Out, w);
  else            conv_iter<A, 1, MODE><<<grid, block, 0, s>>>(P0, P1, Nrm, Out, w);
}

extern "C" void kernel_launch(void* const* d_in, const int* in_sizes, int n_in,
                              void* d_out, int out_size, void* d_ws, size_t ws_size,
                              hipStream_t stream) {
  const float* X  = (const float*)d_in[0];
  const float* Y  = (const float*)d_in[1];
  const float* Nn = (const float*)d_in[3];
  float* out = (float*)d_out;
  float* tmp = (float*)d_ws;   // needs B*H*W*4 = 33.6 MB of scratch
  const size_t HW = (size_t)HH * WW;
  const int B = in_sizes[0] / (int)HW;   // 2

  float K[3][17][5];
  build_K(K);
  Wts w[3];
  for (int a = 0; a < 3; ++a) memcpy(w[a].w, K[a], sizeof(w[a].w));
  const int m0 = pick_mode(0, K[0]);
  const int m1 = pick_mode(1, K[1]);
  const int m2 = pick_mode(2, K[2]);

  // D1 -> d_out, D2 -> d_ws, X3 -> d_out (never read+write same buffer in a pass)
  launch_iter<0, 0>(m0, X,   Y,       Nn,          out, w[0], B, stream);  // D1
  launch_iter<1, 1>(m1, out, nullptr, Nn + HW,     tmp, w[1], B, stream);  // D2
  launch_iter<2, 2>(m2, tmp, Y,       Nn + 2 * HW, out, w[2], B, stream);  // X3
}